// Round 4
// baseline (442.537 us; speedup 1.0000x reference)
//
#include <hip/hip_runtime.h>
#include <hip/hip_bf16.h>

// Downsample: ternary-quantized conv3x3 stride2 pad1, NCHW.
// x:(32,384,64,64) f32, w:(384,384,3,3) f32, bias:(384,) f32 -> out:(32,384,32,32) f32
// Implicit GEMM: M=32768 (n,oh,ow), N=384 (o), K=3456 ((kh,kw,c)), bf16 MFMA.
// Round 7: single-barrier K-step + 32x32x16 MFMA.
//   - ONE EDGE per step (vmcnt(2) + s_barrier): with a barrier per step all
//     waves occupy the same step-window, so lW-double/lX-triple buffering is
//     WAR-safe with no mid-step barrier and NO sched fences inside the step.
//   - All 20 frag ds_reads issued 2-chunks ahead (double-buffered frag regs);
//     compiler inserts fine-grained lgkmcnt -> ds_read latency hides under
//     MFMA clusters (R3's per-phase sched_barrier(0) fences forbade exactly
//     this overlap and serialized read->drain->MFMA 4x per step).
//   - v_mfma_f32_32x32x16_bf16: 2495 vs 2176 TF pipe rate, 24 instead of 48
//     MFMAs per wave-step, same operand bytes, same <=2-way LDS alias.
//   - Staging identical to R3 (verified): W(t+1) issued top-of-t (full-step
//     cover, L2-hot), X(t+2) issued top-of-t (2-step cover, HBM-cold).
// Deterministic: no atomics anywhere.

#define CIN   384
#define HIN   64
#define WIN   64
#define OHW   32
#define KDIM  3456          // 9*384
#define NWELT 1327104       // 384*384*9
#define MDIM  32768         // 32*32*32
#define NT    54            // K-steps of 64; t = khkw*6 + cc  (k = t*64)

using bf16 = __hip_bfloat16;
typedef __attribute__((ext_vector_type(8))) short short8;     // MFMA A/B frag (8 bf16)
typedef __attribute__((ext_vector_type(16))) float floatx16;  // 32x32 C/D frag
typedef __attribute__((ext_vector_type(2))) unsigned short ushort2v;

#define AS1 __attribute__((address_space(1)))
#define AS3 __attribute__((address_space(3)))
#define DMA16(g, l) __builtin_amdgcn_global_load_lds((const AS1 void*)(g), (AS3 void*)(l), 16, 0, 0)

// step edge: counted vmem wait + raw barrier + sched fence (the ONLY fence).
#define EDGE_V(N) do { \
    asm volatile("s_waitcnt vmcnt(" #N ")" ::: "memory"); \
    __builtin_amdgcn_s_barrier(); \
    __builtin_amdgcn_sched_barrier(0); \
} while (0)

// ws layout (floats): [0]=alpha, [1]=thr, [2..64)=62 partials; f[16..20) is
// REUSED as a 16B zero region (written by absum_final AFTER consuming partials).
// bytes [256, 256+100663296): x_nhwc bf16 [32][64][64][384]
// bytes [256+100663296, +2654208): Wq bf16 [384][3456] (k=(kh*3+kw)*384+c)
#define NPART  62
#define ZG_F   16
#define XN_OFF 256
#define WQ_OFF (256 + 100663296)

// ---- Stage 1: fixed-slot partial sums of |w| (no atomics -> deterministic) ----
__global__ void absum_part(const float* __restrict__ w, float* __restrict__ ws) {
    const float4* w4 = (const float4*)w;
    float s = 0.f;
    for (int i = blockIdx.x * 256 + threadIdx.x; i < NWELT / 4; i += NPART * 256) {
        float4 v = w4[i];
        s += fabsf(v.x) + fabsf(v.y) + fabsf(v.z) + fabsf(v.w);
    }
    for (int off = 32; off; off >>= 1) s += __shfl_down(s, off, 64);
    __shared__ float red[4];
    if ((threadIdx.x & 63) == 0) red[threadIdx.x >> 6] = s;
    __syncthreads();
    if (threadIdx.x == 0) ws[2 + blockIdx.x] = red[0] + red[1] + red[2] + red[3];
}

// ---- Stage 2: fixed-order final reduction; also zero the DMA guard region ----
__global__ void absum_final(float* __restrict__ ws) {
    if (threadIdx.x == 0) {
        float s = 0.f;
        for (int i = 0; i < NPART; ++i) s += ws[2 + i];
        float alpha = s * (1.0f / NWELT);
        ws[0] = alpha;
        ws[1] = 1e-3f * alpha;
        ws[ZG_F + 0] = 0.f; ws[ZG_F + 1] = 0.f;   // 16B zero guard (partials dead now)
        ws[ZG_F + 2] = 0.f; ws[ZG_F + 3] = 0.f;
    }
}

// ---- Ternary quantize, output-indexed (coalesced 2B writes; reads L2/L3-hot) ----
__global__ void quant_kernel(const float* __restrict__ w, const float* __restrict__ ws,
                             bf16* __restrict__ wq) {
    int j = blockIdx.x * 256 + threadIdx.x;   // j = o*3456 + (kh*3+kw)*384 + c
    if (j >= NWELT) return;
    float thr = ws[1];
    int o = j / KDIM;
    int rmd = j - o * KDIM;
    int khkw = rmd / 384;
    int c = rmd - khkw * 384;
    float v = w[((o * 384 + c) * 9) + khkw];
    float q = (v > thr) ? 1.f : ((v < -thr) ? -1.f : 0.f);
    wq[j] = __float2bfloat16(q);
}

// ---- NCHW f32 -> NHWC bf16. Block: 64c x 64w for one (n,h). grid=(2048, 6). ----
__global__ void nhwc_kernel(const float* __restrict__ x, bf16* __restrict__ xn) {
    int nh = blockIdx.x;
    int n = nh >> 6, h = nh & 63;
    int c0 = blockIdx.y * 64;
    __shared__ bf16 tile[64][66];   // stride 66: column reads ~conflict-free (33c banks)
    const float* src = x + ((n * CIN + c0) * HIN + h) * WIN;  // c-row stride 4096 floats
    for (int i = 0; i < 4; ++i) {
        int s = threadIdx.x + i * 256;     // [0,1024): 64c x 16 float4
        int cl = s >> 4, w4 = (s & 15) * 4;
        float4 v = *(const float4*)(src + cl * 4096 + w4);
        bf16 t0[2], t1[2];
        t0[0] = __float2bfloat16(v.x); t0[1] = __float2bfloat16(v.y);
        t1[0] = __float2bfloat16(v.z); t1[1] = __float2bfloat16(v.w);
        *(ushort2v*)&tile[cl][w4]     = *(ushort2v*)t0;   // 4B aligned
        *(ushort2v*)&tile[cl][w4 + 2] = *(ushort2v*)t1;
    }
    __syncthreads();
    bf16* dst = xn + ((size_t)(n * HIN + h) * WIN) * CIN + c0;
    for (int i = 0; i < 2; ++i) {
        int q = threadIdx.x + i * 256;     // [0,512): 64w x 8 c-octets
        int wc = q >> 3, c8 = (q & 7) * 8;
        bf16 tmp[8];
        #pragma unroll
        for (int j = 0; j < 8; ++j) tmp[j] = tile[c8 + j][wc];
        *(short8*)(dst + (size_t)wc * CIN + c8) = *(short8*)tmp;
    }
}

// ---- GEMM: D[o][m] = sum_k Wq[o][k] * X[m][k]. A=Wq (384 rows), B=X (128 rows). ----
// 8 waves: io=wv&3 -> o = io*96 + fo*32 (fo<3); im=wv>>2 -> m = im*64 + fm*32 (fm<2).
// Per K-step: c in 0..3 (K=16 chunks): 5 ds_read_b128 + 6 v_mfma_f32_32x32x16_bf16.
// Frag regs double-buffered (cb=c&1); reads for c+2 issued before MFMA of c.
// Ledger (per wave): enter t with [2 X(t+1)]; +6 W(t+1) +2 X(t+2) = 10;
//   EDGE_V(2) retires X(t+1)+W(t+1). One barrier per step -> all waves share
//   the step-window -> lW dbuf + lX tribuf WAR-safe, no other sync needed.
// LDS row (64 k, 128B): slot(r,oct)=r*128+(oct^(r&7))*16; DMA dest linear
// (wave-uniform base + lane*16), global src pre-swizzled g=(lane&7)^(lane>>3).
// Read: og = c*2 + (lane>>5) -> addr r*128 + ((og^(lane&7))*16, r = base+(lane&31):
// per 16-lane quarter-group 8 distinct bank-quads x2 lanes -> free 2-way alias.
// 32x32x16 frags: A/B row = lane&31, k = (lane>>5)*8+j; C/D col(m)=lane&31,
// row(o) = (reg&3) + 8*(reg>>2) + 4*(lane>>5)   [m74/m101 verified layout].
#define BM  128

__global__ __launch_bounds__(512, 2) void conv_gemm(const bf16* __restrict__ xn,
                                                    const bf16* __restrict__ wq,
                                                    const float* __restrict__ ws,
                                                    const float* __restrict__ bias,
                                                    float* __restrict__ out,
                                                    const bf16* __restrict__ zg) {
    __shared__ __align__(16) bf16 lW[2][384 * 64];   // 96 KiB
    __shared__ __align__(16) bf16 lX[3][128 * 64];   // 48 KiB  (total 144 KiB)
    const int m_base = blockIdx.x * BM;              // 256 blocks = 1/CU
    const int tid = threadIdx.x;
    const int lane = tid & 63;
    const int wv = tid >> 6;          // 0..7
    const int io = wv & 3;            // o wave-position (x96)
    const int im = wv >> 2;           // m wave-position (x64)
    const int g = (lane & 7) ^ (lane >> 3);          // pre-swizzled global octet

    // ---- W staging descriptors (verified R3 layout) ----
    const bf16* pw[2][3];
    int wLoff[2][3];
    #pragma unroll
    for (int h = 0; h < 2; ++h)
        #pragma unroll
        for (int j = 0; j < 3; ++j) {
            int rr = h * 192 + wv * 24 + j * 8;
            pw[h][j] = wq + (size_t)(rr + (lane >> 3)) * KDIM + g * 8;
            wLoff[h][j] = rr * 64;
        }

    // ---- X staging descriptors (verified R3 layout) ----
    const bf16* pxn[2];
    int oh2[2], ow2[2], xLoff[2];
    #pragma unroll
    for (int h = 0; h < 2; ++h) {
        int rr = h * 64 + wv * 8;
        int m = m_base + rr + (lane >> 3);
        int n = m >> 10, oh = (m >> 5) & 31, ow = m & 31;
        pxn[h] = xn + (size_t)n * (HIN * WIN * CIN) + g * 8;
        oh2[h] = 2 * oh - 1;
        ow2[h] = 2 * ow - 1;
        xLoff[h] = rr * 64;
    }

    // ---- ds_read byte offsets (32x32x16 fragments) ----
    const int l31 = lane & 31, hi = lane >> 5, l7 = lane & 7;
    int abase[3], bbase[2], octoff[4];
    #pragma unroll
    for (int fo = 0; fo < 3; ++fo) abase[fo] = (io * 96 + fo * 32 + l31) * 128;
    #pragma unroll
    for (int fm = 0; fm < 2; ++fm) bbase[fm] = (im * 64 + fm * 32 + l31) * 128;
    #pragma unroll
    for (int c = 0; c < 4; ++c) octoff[c] = ((c * 2 + hi) ^ l7) * 16;

    floatx16 acc[3][2];
    #pragma unroll
    for (int i = 0; i < 3; ++i)
        #pragma unroll
        for (int j = 0; j < 2; ++j)
            #pragma unroll
            for (int r = 0; r < 16; ++r) acc[i][j][r] = 0.f;

    // ---- prologue: X(0)->lX[0], W(0)->lW[0], X(1)->lX[1]; leave X(1) in flight ----
    {
        #pragma unroll
        for (int h = 0; h < 2; ++h) {                 // X(0): khkw=0 (kh=kw=0), cc=0
            int ih = oh2[h], iw = ow2[h];
            const bf16* p = (ih >= 0 && iw >= 0) ? pxn[h] + (ih * WIN + iw) * CIN : zg;
            DMA16(p, &lX[0][xLoff[h]]);
        }
        #pragma unroll
        for (int h = 0; h < 2; ++h)                   // W(0)
            #pragma unroll
            for (int j = 0; j < 3; ++j) DMA16(pw[h][j], &lW[0][wLoff[h][j]]);
        #pragma unroll
        for (int h = 0; h < 2; ++h) {                 // X(1): khkw=0, cc=1
            int ih = oh2[h], iw = ow2[h];
            const bf16* p = (ih >= 0 && iw >= 0) ? pxn[h] + (ih * WIN + iw) * CIN + 64 : zg;
            DMA16(p, &lX[1][xLoff[h]]);
        }
        EDGE_V(2);   // X(0)+W(0) landed; [2 X(1)] in flight -> steady-state invariant
    }

    short8 afr[2][3], bfr[2][2];

#define READC(CB, C) do { \
    _Pragma("unroll") \
    for (int fo = 0; fo < 3; ++fo) \
        afr[CB][fo] = *(const short8*)((const char*)lWc + abase[fo] + octoff[C]); \
    _Pragma("unroll") \
    for (int fm = 0; fm < 2; ++fm) \
        bfr[CB][fm] = *(const short8*)((const char*)lXc + bbase[fm] + octoff[C]); \
} while (0)

#define MFMAC(CB) do { \
    __builtin_amdgcn_s_setprio(1); \
    _Pragma("unroll") \
    for (int fo = 0; fo < 3; ++fo) \
        _Pragma("unroll") \
        for (int fm = 0; fm < 2; ++fm) \
            acc[fo][fm] = __builtin_amdgcn_mfma_f32_32x32x16_bf16( \
                afr[CB][fo], bfr[CB][fm], acc[fo][fm], 0, 0, 0); \
    __builtin_amdgcn_s_setprio(0); \
} while (0)

    for (int t = 0; t < NT - 1; ++t) {               // t = 0..52
        const bf16* lWc = lW[t & 1];
        const bf16* lXc = lX[t % 3];
        bf16* lWn = lW[(t + 1) & 1];
        bf16* lXn2 = lX[(t + 2) % 3];
        const int kW = (t + 1) * 64;                 // W k-offset for step t+1 (linear)
        const int s2 = t + 2;                        // X staging step
        const int khkw2 = s2 / 6, cc2 = s2 - khkw2 * 6;
        const int kh2 = khkw2 / 3, kw2 = khkw2 - kh2 * 3;

        // frag reads for c=0,1 (compiler staggers lgkmcnt under the DMAs/MFMAs)
        READC(0, 0);
        READC(1, 1);
        // staging: W(t+1) full-step cover (L2-hot), X(t+2) two-step cover (HBM)
        #pragma unroll
        for (int h = 0; h < 2; ++h)
            #pragma unroll
            for (int j = 0; j < 3; ++j) DMA16(pw[h][j] + kW, lWn + wLoff[h][j]);
        #pragma unroll
        for (int h = 0; h < 2; ++h) {
            int ih = oh2[h] + kh2, iw = ow2[h] + kw2;
            bool valid = (ih >= 0) & (iw >= 0) & (s2 < NT);
            const bf16* p = valid ? pxn[h] + (ih * WIN + iw) * CIN + cc2 * 64 : zg;
            DMA16(p, lXn2 + xLoff[h]);
        }
        // pipelined compute: MFMA(c) overlaps reads(c+2)
        MFMAC(0);
        READC(0, 2);
        MFMAC(1);
        READC(1, 3);
        MFMAC(0);
        MFMAC(1);
        EDGE_V(2);   // retire X(t+1)+W(t+1); keep X(t+2) in flight
    }

    // ---- peeled tail (t = 53): everything resident; no staging, no barrier ----
    {
        const bf16* lWc = lW[1];
        const bf16* lXc = lX[53 % 3];    // lX[2]
        READC(0, 0);
        READC(1, 1);
        MFMAC(0);
        READC(0, 2);
        MFMAC(1);
        READC(1, 3);
        MFMAC(0);
        MFMAC(1);
    }

    // ---- epilogue: o = io*96+fo*32+(reg&3)+8*(reg>>2)+4*hi; m = base+im*64+fm*32+l31 ----
    float alpha = ws[0];
    #pragma unroll
    for (int fo = 0; fo < 3; ++fo) {
        #pragma unroll
        for (int fm = 0; fm < 2; ++fm) {
            int m = m_base + im * 64 + fm * 32 + l31;
            int nn = m >> 10, ohh = (m >> 5) & 31, oww = m & 31;
            #pragma unroll
            for (int r = 0; r < 16; ++r) {
                int o = io * 96 + fo * 32 + (r & 3) + 8 * (r >> 2) + 4 * hi;
                out[((nn * 384 + o) * OHW + ohh) * OHW + oww] = alpha * acc[fo][fm][r] + bias[o];
            }
        }
    }
}

extern "C" void kernel_launch(void* const* d_in, const int* in_sizes, int n_in,
                              void* d_out, int out_size, void* d_ws, size_t ws_size,
                              hipStream_t stream) {
    (void)in_sizes; (void)n_in; (void)out_size; (void)ws_size;
    const float* x    = (const float*)d_in[0];
    const float* w    = (const float*)d_in[1];
    const float* bias = (const float*)d_in[2];
    float* out = (float*)d_out;
    float* wsf = (float*)d_ws;
    bf16* xn = (bf16*)((char*)d_ws + XN_OFF);
    bf16* wq = (bf16*)((char*)d_ws + WQ_OFF);
    const bf16* zg = (const bf16*)(wsf + ZG_F);

    absum_part<<<NPART, 256, 0, stream>>>(w, wsf);
    absum_final<<<1, 64, 0, stream>>>(wsf);
    quant_kernel<<<(NWELT + 255) / 256, 256, 0, stream>>>(w, wsf, wq);
    nhwc_kernel<<<dim3(2048, 6), 256, 0, stream>>>(x, xn);
    conv_gemm<<<dim3(MDIM / BM, 1), 512, 0, stream>>>(xn, wq, wsf, bias, out, zg);
}